// Round 8
// baseline (595.150 us; speedup 1.0000x reference)
//
#include <hip/hip_runtime.h>
#include <hip/hip_bf16.h>
#include <math.h>

#define NNODES 100000
#define NEDGES 500000
#define NB_SCAN 391  // ceil(NNODES/256)

typedef __attribute__((ext_vector_type(8))) short short8;
typedef __attribute__((ext_vector_type(4))) float f32x4;

__device__ __forceinline__ float bf2f(__hip_bfloat16 v) {
  return __bfloat162float(v);
}

// ================= CSR build ==================================================
__global__ void k_deg(const int* __restrict__ ei, int* __restrict__ deg) {
  const int idx = blockIdx.x * 256 + threadIdx.x;
  if (idx < 2 * NEDGES) atomicAdd(&deg[ei[NEDGES + idx]], 1);
}

__global__ void k_scan1(const int* __restrict__ deg, int* __restrict__ offs,
                        int* __restrict__ bsums) {
  __shared__ int sh[256];
  const int t = threadIdx.x;
  const int i = blockIdx.x * 256 + t;
  const int v = (i < NNODES) ? deg[i] : 0;
  sh[t] = v;
  __syncthreads();
  for (int d = 1; d < 256; d <<= 1) {
    const int add = (t >= d) ? sh[t - d] : 0;
    __syncthreads();
    sh[t] += add;
    __syncthreads();
  }
  if (i < NNODES) offs[i] = sh[t] - v;  // exclusive
  if (t == 255) bsums[blockIdx.x] = sh[255];
}

__global__ void k_scan2(int* __restrict__ bsums) {
  __shared__ int sh[512];
  const int t = threadIdx.x;
  const int v = (t < NB_SCAN) ? bsums[t] : 0;
  sh[t] = v;
  __syncthreads();
  for (int d = 1; d < 512; d <<= 1) {
    const int add = (t >= d) ? sh[t - d] : 0;
    __syncthreads();
    sh[t] += add;
    __syncthreads();
  }
  if (t < NB_SCAN) bsums[t] = sh[t] - v;  // exclusive
}

__global__ void k_scan3(int* __restrict__ offs, const int* __restrict__ bsums,
                        int* __restrict__ cursor) {
  const int i = blockIdx.x * 256 + threadIdx.x;
  if (i < NNODES) {
    const int o = offs[i] + bsums[blockIdx.x];
    offs[i] = o;
    cursor[i] = o;
  }
  if (i == 0) offs[NNODES] = 2 * NEDGES;
}

// Fill packed slot records: (drug, other | role<<30).
__global__ void k_fill3(const int* __restrict__ ei, int* __restrict__ cursor,
                        int2* __restrict__ recA) {
  const int idx = blockIdx.x * 256 + threadIdx.x;
  if (idx >= 2 * NEDGES) return;
  const int n = ei[NEDGES + idx];
  const int e = (idx < NEDGES) ? idx : idx - NEDGES;
  const int drug = ei[e];
  const int other = (idx < NEDGES) ? ei[2 * NEDGES + e] : ei[NEDGES + e];
  const int role = (idx < NEDGES) ? 0 : 1;
  const int pos = atomicAdd(&cursor[n], 1);
  recA[pos] = make_int2(drug, other | (role << 30));
}

// ========== B-matrix prep for layer-0 MFMA GEMM (K=64, 272 cols) ==============
__global__ void k_prep0(const float* __restrict__ W0, const float* __restrict__ a1,
                        const float* __restrict__ a2, const float* __restrict__ a3,
                        __hip_bfloat16* __restrict__ B0) {
  const int t = blockIdx.x * 256 + threadIdx.x;  // < 17408
  const int j = t & 7, l = (t >> 3) & 63, s = (t >> 9) & 1, g = t >> 10;
  const int k = s * 32 + ((l >> 4) << 3) + j;
  const int col = g * 16 + (l & 15);
  float v = 0.f;
  if (col < 256) {
    v = W0[col * 64 + k];
  } else if (col < 268) {
    const int idx = col - 256;
    const int r = idx >> 2, h = idx & 3;
    const float* av = (r == 0) ? a1 : (r == 1) ? a2 : a3;
    for (int f = 0; f < 64; ++f)
      v = fmaf(av[h * 64 + f], W0[(h * 64 + f) * 64 + k], v);
  }
  B0[t] = __float2bfloat16(v);
}

// ========== B-matrix prep for layer-1 MFMA GEMM (K=256, 144 cols) =============
__global__ void k_prepw1(const float* __restrict__ W1,
                         const float* __restrict__ Wskip1,
                         const float* __restrict__ a1, const float* __restrict__ a2,
                         const float* __restrict__ a3,
                         __hip_bfloat16* __restrict__ B1) {
  const int t = blockIdx.x * 256 + threadIdx.x;  // < 36864
  const int j = t & 7, l = (t >> 3) & 63, s = (t >> 9) & 7, g = t >> 12;
  const int k = s * 32 + ((l >> 4) << 3) + j;
  const int col = g * 16 + (l & 15);
  float v = 0.f;
  if (col < 64) {
    v = W1[col * 256 + k];
  } else if (col < 128) {
    v = Wskip1[(col - 64) * 256 + k];
  } else if (col < 131) {
    const int r = col - 128;
    const float* av = (r == 0) ? a1 : (r == 1) ? a2 : a3;
    for (int f = 0; f < 64; ++f) v = fmaf(av[f], W1[f * 256 + k], v);
  }
  B1[t] = __float2bfloat16(v);
}

// ================= Layer-0 MFMA GEMM: [N,64] x [64,272] =======================
#define LDA0 72
__global__ __launch_bounds__(256) void k_mm0(
    const float* __restrict__ x, const short* __restrict__ B0,
    __hip_bfloat16* __restrict__ proj0, float* __restrict__ s1,
    float* __restrict__ s2, float* __restrict__ s3) {
  __shared__ __hip_bfloat16 As[64 * LDA0];
  const int t = threadIdx.x;
  const int lane = t & 63, w = t >> 6;
  const int base = blockIdx.x * 64;
  for (int q = 0; q < 4; ++q) {
    const int i = q * 256 + t;
    const int r = i >> 4;
    const int c4 = i & 15;
    int rg = base + r;
    if (rg >= NNODES) rg = NNODES - 1;
    const float4 v = ((const float4*)(x + (size_t)rg * 64))[c4];
    __hip_bfloat16* dst = &As[r * LDA0 + c4 * 4];
    dst[0] = __float2bfloat16(v.x);
    dst[1] = __float2bfloat16(v.y);
    dst[2] = __float2bfloat16(v.z);
    dst[3] = __float2bfloat16(v.w);
  }
  __syncthreads();
  const short8* B8 = (const short8*)B0;
  f32x4 acc[17];
#pragma unroll
  for (int g = 0; g < 17; ++g) acc[g] = (f32x4){0.f, 0.f, 0.f, 0.f};
  const int aoff = (w * 16 + (lane & 15)) * LDA0 + (lane >> 4) * 8;
#pragma unroll
  for (int s = 0; s < 2; ++s) {
    const short8 af = *(const short8*)(&As[aoff + s * 32]);
#pragma unroll
    for (int g = 0; g < 17; ++g) {
      const short8 bf = B8[(g * 2 + s) * 64 + lane];
      acc[g] = __builtin_amdgcn_mfma_f32_16x16x32_bf16(af, bf, acc[g], 0, 0, 0);
    }
  }
  const int r0 = base + w * 16 + (lane >> 4) * 4;
  const int cn = lane & 15;
#pragma unroll
  for (int g = 0; g < 16; ++g) {
    const int col = g * 16 + cn;
#pragma unroll
    for (int r = 0; r < 4; ++r) {
      const int row = r0 + r;
      if (row < NNODES)
        proj0[(size_t)row * 256 + col] = __float2bfloat16(acc[g][r]);
    }
  }
#pragma unroll
  for (int r = 0; r < 4; ++r) {
    const int row = r0 + r;
    if (row < NNODES) {
      if (cn < 4) s1[row * 4 + cn] = acc[16][r];
      else if (cn < 8) s2[row * 4 + (cn - 4)] = acc[16][r];
      else if (cn < 12) s3[row * 4 + (cn - 8)] = acc[16][r];
    }
  }
}

// ====== Layer-0 exp-scores per slot (node order) + denominator sums ===========
__global__ void k_sums0x(const int* __restrict__ offs, const int2* __restrict__ recA,
                         const float* __restrict__ s1, const float* __restrict__ s2,
                         const float* __restrict__ s3, float* __restrict__ esx,
                         float* __restrict__ sums) {
  const int n = blockIdx.x * 256 + threadIdx.x;
  if (n >= NNODES) return;
  const int beg = offs[n], end = offs[n + 1];
  const float4 s2n = ((const float4*)s2)[n];
  const float4 s3n = ((const float4*)s3)[n];
  float4 acc = make_float4(0.f, 0.f, 0.f, 0.f);
  for (int j = beg; j < end; ++j) {
    const int2 rec = recA[j];
    const int o = rec.y & 0x3FFFFFFF;
    const int role = rec.y >> 30;
    const float4 A = ((const float4*)s1)[rec.x];
    const float4 O = role ? ((const float4*)s2)[o] : ((const float4*)s3)[o];
    const float4 S = role ? s3n : s2n;
    float4 es;
    float s;
    s = A.x + O.x + S.x; s = s > 0.f ? s : 0.2f * s; es.x = __expf(s);
    s = A.y + O.y + S.y; s = s > 0.f ? s : 0.2f * s; es.y = __expf(s);
    s = A.z + O.z + S.z; s = s > 0.f ? s : 0.2f * s; es.z = __expf(s);
    s = A.w + O.w + S.w; s = s > 0.f ? s : 0.2f * s; es.w = __expf(s);
    ((float4*)esx)[j] = es;
    acc.x += es.x; acc.y += es.y; acc.z += es.z; acc.w += es.w;
  }
  ((float4*)sums)[n] = acc;
}

// ====== FUSED: layer-0 aggregate (att on the fly) -> LDS -> layer-1 MFMA ======
// Block = 64-node tile. Phase 1: wave w aggregates nodes w*16..w*16+15 into
// LDS A rows (skip+bias+elu, bf16). Phase 2: [64,256]x[256,144] MFMA.
#define LDA1 264
__global__ __launch_bounds__(256) void k_fuse0(
    const int* __restrict__ offs, const int2* __restrict__ recA,
    const float* __restrict__ esx, const float* __restrict__ sums,
    const __hip_bfloat16* __restrict__ proj0, const float* __restrict__ x,
    const float* __restrict__ b0, const short* __restrict__ B1,
    const float* __restrict__ b1, __hip_bfloat16* __restrict__ proj1,
    float* __restrict__ out, float* __restrict__ s1, float* __restrict__ s2,
    float* __restrict__ s3) {
  __shared__ short As[64 * LDA1];
  const int t = threadIdx.x;
  const int lane = t & 63, w = t >> 6;
  const int base = blockIdx.x * 64;
  __hip_bfloat16* Ah = (__hip_bfloat16*)As;
  const float b00 = b0[lane], b01 = b0[64 + lane];
  const float b02 = b0[128 + lane], b03 = b0[192 + lane];
  // ---- phase 1 ----
  for (int i = 0; i < 16; ++i) {
    const int r = w * 16 + i;
    int n = base + r;
    if (n >= NNODES) n = NNODES - 1;  // dup work; stores guarded in phase 2
    const int beg = offs[n], end = offs[n + 1];
    const float4 sn = ((const float4*)sums)[n];
    float a0 = 0.f, a1 = 0.f, a2 = 0.f, a3 = 0.f;
    int j = beg;
    for (; j + 1 < end; j += 2) {
      const int2 rA = recA[j], rB = recA[j + 1];
      const float4 eA = ((const float4*)esx)[j];
      const float4 eB = ((const float4*)esx)[j + 1];
      const float4 soA = ((const float4*)sums)[rA.y & 0x3FFFFFFF];
      const float4 soB = ((const float4*)sums)[rB.y & 0x3FFFFFFF];
      const __hip_bfloat16* pA = proj0 + (size_t)rA.x * 256 + lane;
      const __hip_bfloat16* pB = proj0 + (size_t)rB.x * 256 + lane;
      const float tA0 = eA.x * __builtin_amdgcn_rcpf(sn.x + soA.x + 1e-16f);
      const float tA1 = eA.y * __builtin_amdgcn_rcpf(sn.y + soA.y + 1e-16f);
      const float tA2 = eA.z * __builtin_amdgcn_rcpf(sn.z + soA.z + 1e-16f);
      const float tA3 = eA.w * __builtin_amdgcn_rcpf(sn.w + soA.w + 1e-16f);
      const float tB0 = eB.x * __builtin_amdgcn_rcpf(sn.x + soB.x + 1e-16f);
      const float tB1 = eB.y * __builtin_amdgcn_rcpf(sn.y + soB.y + 1e-16f);
      const float tB2 = eB.z * __builtin_amdgcn_rcpf(sn.z + soB.z + 1e-16f);
      const float tB3 = eB.w * __builtin_amdgcn_rcpf(sn.w + soB.w + 1e-16f);
      a0 = fmaf(bf2f(pA[0]), tA0, a0);
      a1 = fmaf(bf2f(pA[64]), tA1, a1);
      a2 = fmaf(bf2f(pA[128]), tA2, a2);
      a3 = fmaf(bf2f(pA[192]), tA3, a3);
      a0 = fmaf(bf2f(pB[0]), tB0, a0);
      a1 = fmaf(bf2f(pB[64]), tB1, a1);
      a2 = fmaf(bf2f(pB[128]), tB2, a2);
      a3 = fmaf(bf2f(pB[192]), tB3, a3);
    }
    if (j < end) {
      const int2 rA = recA[j];
      const float4 eA = ((const float4*)esx)[j];
      const float4 soA = ((const float4*)sums)[rA.y & 0x3FFFFFFF];
      const __hip_bfloat16* pA = proj0 + (size_t)rA.x * 256 + lane;
      a0 = fmaf(bf2f(pA[0]),
                eA.x * __builtin_amdgcn_rcpf(sn.x + soA.x + 1e-16f), a0);
      a1 = fmaf(bf2f(pA[64]),
                eA.y * __builtin_amdgcn_rcpf(sn.y + soA.y + 1e-16f), a1);
      a2 = fmaf(bf2f(pA[128]),
                eA.z * __builtin_amdgcn_rcpf(sn.z + soA.z + 1e-16f), a2);
      a3 = fmaf(bf2f(pA[192]),
                eA.w * __builtin_amdgcn_rcpf(sn.w + soA.w + 1e-16f), a3);
    }
    const float xs = x[(size_t)n * 64 + lane];
    float v0 = a0 + xs + b00;
    float v1 = a1 + xs + b01;
    float v2 = a2 + xs + b02;
    float v3 = a3 + xs + b03;
    v0 = v0 > 0.f ? v0 : expm1f(v0);
    v1 = v1 > 0.f ? v1 : expm1f(v1);
    v2 = v2 > 0.f ? v2 : expm1f(v2);
    v3 = v3 > 0.f ? v3 : expm1f(v3);
    Ah[r * LDA1 + lane] = __float2bfloat16(v0);
    Ah[r * LDA1 + 64 + lane] = __float2bfloat16(v1);
    Ah[r * LDA1 + 128 + lane] = __float2bfloat16(v2);
    Ah[r * LDA1 + 192 + lane] = __float2bfloat16(v3);
  }
  __syncthreads();
  // ---- phase 2: MFMA over the LDS tile ----
  const short8* B8 = (const short8*)B1;
  f32x4 acc[9];
#pragma unroll
  for (int g = 0; g < 9; ++g) acc[g] = (f32x4){0.f, 0.f, 0.f, 0.f};
  const int aoff = (w * 16 + (lane & 15)) * LDA1 + (lane >> 4) * 8;
#pragma unroll
  for (int s = 0; s < 8; ++s) {
    const short8 af = *(const short8*)(&As[aoff + s * 32]);
#pragma unroll
    for (int g = 0; g < 9; ++g) {
      const short8 bf = B8[(g * 8 + s) * 64 + lane];
      acc[g] = __builtin_amdgcn_mfma_f32_16x16x32_bf16(af, bf, acc[g], 0, 0, 0);
    }
  }
  const int r0 = base + w * 16 + (lane >> 4) * 4;
  const int cn = lane & 15;
#pragma unroll
  for (int g = 0; g < 4; ++g) {
    const int col = g * 16 + cn;
#pragma unroll
    for (int r = 0; r < 4; ++r) {
      const int row = r0 + r;
      if (row < NNODES)
        proj1[(size_t)row * 64 + col] = __float2bfloat16(acc[g][r]);
    }
  }
#pragma unroll
  for (int g = 4; g < 8; ++g) {
    const int col = (g - 4) * 16 + cn;
    const float bv = b1[col];
#pragma unroll
    for (int r = 0; r < 4; ++r) {
      const int row = r0 + r;
      if (row < NNODES) out[(size_t)row * 64 + col] = acc[g][r] + bv;
    }
  }
#pragma unroll
  for (int r = 0; r < 4; ++r) {
    const int row = r0 + r;
    if (row < NNODES) {
      if (cn == 0) s1[row] = acc[8][r];
      else if (cn == 1) s2[row] = acc[8][r];
      else if (cn == 2) s3[row] = acc[8][r];
    }
  }
}

// ====== Layer-1 exp-scores per slot + denominator sums ========================
__global__ void k_sums1x(const int* __restrict__ offs, const int2* __restrict__ recA,
                         const float* __restrict__ s1, const float* __restrict__ s2,
                         const float* __restrict__ s3, float* __restrict__ es1,
                         float* __restrict__ sums) {
  const int n = blockIdx.x * 256 + threadIdx.x;
  if (n >= NNODES) return;
  const int beg = offs[n], end = offs[n + 1];
  const float s2n = s2[n], s3n = s3[n];
  float acc = 0.f;
  for (int j = beg; j < end; ++j) {
    const int2 rec = recA[j];
    const int o = rec.y & 0x3FFFFFFF;
    const int role = rec.y >> 30;
    const float ov = role ? s2[o] : s3[o];
    const float sv = role ? s3n : s2n;
    float s = s1[rec.x] + ov + sv;
    s = s > 0.f ? s : 0.2f * s;
    const float e = __expf(s);
    es1[j] = e;
    acc += e;
  }
  sums[n] = acc;
}

// ========== Layer-1 aggregate, wave per node, att on the fly ==================
__global__ __launch_bounds__(256) void k_agg1(
    const int* __restrict__ offs, const int2* __restrict__ recA,
    const float* __restrict__ es1, const float* __restrict__ sums,
    const __hip_bfloat16* __restrict__ proj1, float* __restrict__ dout) {
  const int lane = threadIdx.x & 63, wid = threadIdx.x >> 6;
  const int n = blockIdx.x * 4 + wid;
  if (n >= NNODES) return;
  const int beg = offs[n], end = offs[n + 1];
  const float sn = sums[n];
  float acc0 = 0.f, acc1 = 0.f;
  int j = beg;
  for (; j + 1 < end; j += 2) {
    const int2 rA = recA[j], rB = recA[j + 1];
    const float eA = es1[j], eB = es1[j + 1];
    const float soA = sums[rA.y & 0x3FFFFFFF];
    const float soB = sums[rB.y & 0x3FFFFFFF];
    const float pA = bf2f(proj1[(unsigned)(rA.x * 64 + lane)]);
    const float pB = bf2f(proj1[(unsigned)(rB.x * 64 + lane)]);
    acc0 = fmaf(pA, eA * __builtin_amdgcn_rcpf(sn + soA + 1e-16f), acc0);
    acc1 = fmaf(pB, eB * __builtin_amdgcn_rcpf(sn + soB + 1e-16f), acc1);
  }
  if (j < end) {
    const int2 rA = recA[j];
    const float soA = sums[rA.y & 0x3FFFFFFF];
    acc0 = fmaf(bf2f(proj1[(unsigned)(rA.x * 64 + lane)]),
                es1[j] * __builtin_amdgcn_rcpf(sn + soA + 1e-16f), acc0);
  }
  dout[(size_t)n * 64 + lane] += acc0 + acc1;
}

extern "C" void kernel_launch(void* const* d_in, const int* in_sizes, int n_in,
                              void* d_out, int out_size, void* d_ws, size_t ws_size,
                              hipStream_t stream) {
  const float* x = (const float*)d_in[0];
  const int* ei = (const int*)d_in[1];
  const float* W0 = (const float*)d_in[2];
  const float* a10 = (const float*)d_in[3];
  const float* a20 = (const float*)d_in[4];
  const float* a30 = (const float*)d_in[5];
  // d_in[6] = Wskip0: unused (layer-0 skip is identity, F==DIN)
  const float* b0 = (const float*)d_in[7];
  const float* W1 = (const float*)d_in[8];
  const float* a11 = (const float*)d_in[9];
  const float* a21 = (const float*)d_in[10];
  const float* a31 = (const float*)d_in[11];
  const float* Wskip1 = (const float*)d_in[12];
  const float* b1 = (const float*)d_in[13];
  float* out = (float*)d_out;

  // ---- Workspace layout: ~97 MB ----
  __hip_bfloat16* proj0 = (__hip_bfloat16*)d_ws;       // N*256 bf16
  __hip_bfloat16* proj1 = proj0 + (size_t)NNODES * 256;  // N*64 bf16 (separate!)
  float* s1_0 = (float*)(proj1 + (size_t)NNODES * 64);  // N*4 x3
  float* s2_0 = s1_0 + (size_t)NNODES * 4;
  float* s3_0 = s2_0 + (size_t)NNODES * 4;
  float* sums0 = s3_0 + (size_t)NNODES * 4;            // N*4
  float* esx0 = sums0 + (size_t)NNODES * 4;            // 2E*4 (float4/slot)
  int2* recA = (int2*)(esx0 + (size_t)2 * NEDGES * 4); // 2E int2
  int* offs = (int*)(recA + 2 * NEDGES);               // N+16
  float* s1_1 = (float*)(offs + NNODES + 16);          // N x3
  float* s2_1 = s1_1 + NNODES;
  float* s3_1 = s2_1 + NNODES;
  float* sums1 = s3_1 + NNODES;                        // N
  __hip_bfloat16* B0swz = (__hip_bfloat16*)(sums1 + NNODES);  // 17408 bf16
  __hip_bfloat16* B1swz = B0swz + 17408;               // 36864 bf16
  // CSR-build int scratch aliases esx0 (dead until k_sums0x):
  int* deg = (int*)esx0;
  int* cursor = deg + NNODES;
  int* bsums = cursor + NNODES;
  float* es1 = esx0;  // layer-1 raw exp per slot (esx0 dead after k_fuse0)

  // ---- weight prep (independent) ----
  k_prep0<<<68, 256, 0, stream>>>(W0, a10, a20, a30, B0swz);
  k_prepw1<<<144, 256, 0, stream>>>(W1, Wskip1, a11, a21, a31, B1swz);

  // ---- Layer-0 projection + scores via MFMA ----
  k_mm0<<<(NNODES + 63) / 64, 256, 0, stream>>>(x, (const short*)B0swz, proj0,
                                                s1_0, s2_0, s3_0);

  // ---- CSR build (packed records) ----
  hipMemsetAsync(deg, 0, NNODES * sizeof(int), stream);
  k_deg<<<(2 * NEDGES + 255) / 256, 256, 0, stream>>>(ei, deg);
  k_scan1<<<NB_SCAN, 256, 0, stream>>>(deg, offs, bsums);
  k_scan2<<<1, 512, 0, stream>>>(bsums);
  k_scan3<<<NB_SCAN, 256, 0, stream>>>(offs, bsums, cursor);
  k_fill3<<<(2 * NEDGES + 255) / 256, 256, 0, stream>>>(ei, cursor, recA);

  // ---- Layer 0: slot exp-scores + sums, then fused agg+GEMM ----
  k_sums0x<<<NB_SCAN, 256, 0, stream>>>(offs, recA, s1_0, s2_0, s3_0, esx0,
                                        sums0);
  k_fuse0<<<(NNODES + 63) / 64, 256, 0, stream>>>(
      offs, recA, esx0, sums0, proj0, x, b0, (const short*)B1swz, b1, proj1,
      out, s1_1, s2_1, s3_1);

  // ---- Layer 1: slot exp-scores + sums, then aggregate ----
  k_sums1x<<<NB_SCAN, 256, 0, stream>>>(offs, recA, s1_1, s2_1, s3_1, es1,
                                        sums1);
  k_agg1<<<(NNODES + 3) / 4, 256, 0, stream>>>(offs, recA, es1, sums1, proj1,
                                               out);
}

// Round 9
// 549.298 us; speedup vs baseline: 1.0835x; 1.0835x over previous
//
#include <hip/hip_runtime.h>
#include <hip/hip_bf16.h>
#include <math.h>

#define NNODES 100000
#define NEDGES 500000
#define NB_SCAN 391  // ceil(NNODES/256)

typedef __attribute__((ext_vector_type(8))) short short8;
typedef __attribute__((ext_vector_type(4))) float f32x4;

__device__ __forceinline__ float bf2f(__hip_bfloat16 v) {
  return __bfloat162float(v);
}

// ================= CSR build ==================================================
__global__ void k_deg(const int* __restrict__ ei, int* __restrict__ deg) {
  const int idx = blockIdx.x * 256 + threadIdx.x;
  if (idx < 2 * NEDGES) atomicAdd(&deg[ei[NEDGES + idx]], 1);
}

__global__ void k_scan1(const int* __restrict__ deg, int* __restrict__ offs,
                        int* __restrict__ bsums) {
  __shared__ int sh[256];
  const int t = threadIdx.x;
  const int i = blockIdx.x * 256 + t;
  const int v = (i < NNODES) ? deg[i] : 0;
  sh[t] = v;
  __syncthreads();
  for (int d = 1; d < 256; d <<= 1) {
    const int add = (t >= d) ? sh[t - d] : 0;
    __syncthreads();
    sh[t] += add;
    __syncthreads();
  }
  if (i < NNODES) offs[i] = sh[t] - v;  // exclusive
  if (t == 255) bsums[blockIdx.x] = sh[255];
}

__global__ void k_scan2(int* __restrict__ bsums) {
  __shared__ int sh[512];
  const int t = threadIdx.x;
  const int v = (t < NB_SCAN) ? bsums[t] : 0;
  sh[t] = v;
  __syncthreads();
  for (int d = 1; d < 512; d <<= 1) {
    const int add = (t >= d) ? sh[t - d] : 0;
    __syncthreads();
    sh[t] += add;
    __syncthreads();
  }
  if (t < NB_SCAN) bsums[t] = sh[t] - v;  // exclusive
}

__global__ void k_scan3(int* __restrict__ offs, const int* __restrict__ bsums,
                        int* __restrict__ cursor) {
  const int i = blockIdx.x * 256 + threadIdx.x;
  if (i < NNODES) {
    const int o = offs[i] + bsums[blockIdx.x];
    offs[i] = o;
    cursor[i] = o;
  }
  if (i == 0) offs[NNODES] = 2 * NEDGES;
}

// Fill packed slot records: (drug, other | role<<30).
__global__ void k_fill3(const int* __restrict__ ei, int* __restrict__ cursor,
                        int2* __restrict__ recA) {
  const int idx = blockIdx.x * 256 + threadIdx.x;
  if (idx >= 2 * NEDGES) return;
  const int n = ei[NEDGES + idx];
  const int e = (idx < NEDGES) ? idx : idx - NEDGES;
  const int drug = ei[e];
  const int other = (idx < NEDGES) ? ei[2 * NEDGES + e] : ei[NEDGES + e];
  const int role = (idx < NEDGES) ? 0 : 1;
  const int pos = atomicAdd(&cursor[n], 1);
  recA[pos] = make_int2(drug, other | (role << 30));
}

// ========== B-matrix prep for layer-0 MFMA GEMM (K=64, 272 cols) ==============
__global__ void k_prep0(const float* __restrict__ W0, const float* __restrict__ a1,
                        const float* __restrict__ a2, const float* __restrict__ a3,
                        __hip_bfloat16* __restrict__ B0) {
  const int t = blockIdx.x * 256 + threadIdx.x;  // < 17408
  const int j = t & 7, l = (t >> 3) & 63, s = (t >> 9) & 1, g = t >> 10;
  const int k = s * 32 + ((l >> 4) << 3) + j;
  const int col = g * 16 + (l & 15);
  float v = 0.f;
  if (col < 256) {
    v = W0[col * 64 + k];
  } else if (col < 268) {
    const int idx = col - 256;
    const int r = idx >> 2, h = idx & 3;
    const float* av = (r == 0) ? a1 : (r == 1) ? a2 : a3;
    for (int f = 0; f < 64; ++f)
      v = fmaf(av[h * 64 + f], W0[(h * 64 + f) * 64 + k], v);
  }
  B0[t] = __float2bfloat16(v);
}

// ========== B-matrix prep for layer-1 MFMA GEMM (K=256, 144 cols) =============
__global__ void k_prepw1(const float* __restrict__ W1,
                         const float* __restrict__ Wskip1,
                         const float* __restrict__ a1, const float* __restrict__ a2,
                         const float* __restrict__ a3,
                         __hip_bfloat16* __restrict__ B1) {
  const int t = blockIdx.x * 256 + threadIdx.x;  // < 36864
  const int j = t & 7, l = (t >> 3) & 63, s = (t >> 9) & 7, g = t >> 12;
  const int k = s * 32 + ((l >> 4) << 3) + j;
  const int col = g * 16 + (l & 15);
  float v = 0.f;
  if (col < 64) {
    v = W1[col * 256 + k];
  } else if (col < 128) {
    v = Wskip1[(col - 64) * 256 + k];
  } else if (col < 131) {
    const int r = col - 128;
    const float* av = (r == 0) ? a1 : (r == 1) ? a2 : a3;
    for (int f = 0; f < 64; ++f) v = fmaf(av[f], W1[f * 256 + k], v);
  }
  B1[t] = __float2bfloat16(v);
}

// ================= Layer-0 MFMA GEMM: [N,64] x [64,272] =======================
#define LDA0 72
__global__ __launch_bounds__(256) void k_mm0(
    const float* __restrict__ x, const short* __restrict__ B0,
    __hip_bfloat16* __restrict__ proj0, float* __restrict__ s1,
    float* __restrict__ s2, float* __restrict__ s3) {
  __shared__ __hip_bfloat16 As[64 * LDA0];
  const int t = threadIdx.x;
  const int lane = t & 63, w = t >> 6;
  const int base = blockIdx.x * 64;
  for (int q = 0; q < 4; ++q) {
    const int i = q * 256 + t;
    const int r = i >> 4;
    const int c4 = i & 15;
    int rg = base + r;
    if (rg >= NNODES) rg = NNODES - 1;
    const float4 v = ((const float4*)(x + (size_t)rg * 64))[c4];
    __hip_bfloat16* dst = &As[r * LDA0 + c4 * 4];
    dst[0] = __float2bfloat16(v.x);
    dst[1] = __float2bfloat16(v.y);
    dst[2] = __float2bfloat16(v.z);
    dst[3] = __float2bfloat16(v.w);
  }
  __syncthreads();
  const short8* B8 = (const short8*)B0;
  f32x4 acc[17];
#pragma unroll
  for (int g = 0; g < 17; ++g) acc[g] = (f32x4){0.f, 0.f, 0.f, 0.f};
  const int aoff = (w * 16 + (lane & 15)) * LDA0 + (lane >> 4) * 8;
#pragma unroll
  for (int s = 0; s < 2; ++s) {
    const short8 af = *(const short8*)(&As[aoff + s * 32]);
#pragma unroll
    for (int g = 0; g < 17; ++g) {
      const short8 bf = B8[(g * 2 + s) * 64 + lane];
      acc[g] = __builtin_amdgcn_mfma_f32_16x16x32_bf16(af, bf, acc[g], 0, 0, 0);
    }
  }
  const int r0 = base + w * 16 + (lane >> 4) * 4;
  const int cn = lane & 15;
#pragma unroll
  for (int g = 0; g < 16; ++g) {
    const int col = g * 16 + cn;
#pragma unroll
    for (int r = 0; r < 4; ++r) {
      const int row = r0 + r;
      if (row < NNODES)
        proj0[(size_t)row * 256 + col] = __float2bfloat16(acc[g][r]);
    }
  }
#pragma unroll
  for (int r = 0; r < 4; ++r) {
    const int row = r0 + r;
    if (row < NNODES) {
      if (cn < 4) s1[row * 4 + cn] = acc[16][r];
      else if (cn < 8) s2[row * 4 + (cn - 4)] = acc[16][r];
      else if (cn < 12) s3[row * 4 + (cn - 8)] = acc[16][r];
    }
  }
}

// ====== Layer-0 exp-scores per slot (node order) + denominator sums ===========
__global__ void k_sums0x(const int* __restrict__ offs, const int2* __restrict__ recA,
                         const float* __restrict__ s1, const float* __restrict__ s2,
                         const float* __restrict__ s3, float* __restrict__ esx,
                         float* __restrict__ sums) {
  const int n = blockIdx.x * 256 + threadIdx.x;
  if (n >= NNODES) return;
  const int beg = offs[n], end = offs[n + 1];
  const float4 s2n = ((const float4*)s2)[n];
  const float4 s3n = ((const float4*)s3)[n];
  float4 acc = make_float4(0.f, 0.f, 0.f, 0.f);
  for (int j = beg; j < end; ++j) {
    const int2 rec = recA[j];
    const int o = rec.y & 0x3FFFFFFF;
    const int role = rec.y >> 30;
    const float4 A = ((const float4*)s1)[rec.x];
    const float4 O = role ? ((const float4*)s2)[o] : ((const float4*)s3)[o];
    const float4 S = role ? s3n : s2n;
    float4 es;
    float s;
    s = A.x + O.x + S.x; s = s > 0.f ? s : 0.2f * s; es.x = __expf(s);
    s = A.y + O.y + S.y; s = s > 0.f ? s : 0.2f * s; es.y = __expf(s);
    s = A.z + O.z + S.z; s = s > 0.f ? s : 0.2f * s; es.z = __expf(s);
    s = A.w + O.w + S.w; s = s > 0.f ? s : 0.2f * s; es.w = __expf(s);
    ((float4*)esx)[j] = es;
    acc.x += es.x; acc.y += es.y; acc.z += es.z; acc.w += es.w;
  }
  ((float4*)sums)[n] = acc;
}

// ====== Layer-0 aggregate, wave/node, att on the fly, skip+bias+elu ===========
__global__ __launch_bounds__(256) void k_agg0w(
    const int* __restrict__ offs, const int2* __restrict__ recA,
    const float* __restrict__ esx, const float* __restrict__ sums,
    const __hip_bfloat16* __restrict__ proj0, const float* __restrict__ x,
    const float* __restrict__ b0, __hip_bfloat16* __restrict__ out0b) {
  const int lane = threadIdx.x & 63, wid = threadIdx.x >> 6;
  const int n = blockIdx.x * 4 + wid;
  if (n >= NNODES) return;
  const int beg = offs[n], end = offs[n + 1];
  const float4 sn = ((const float4*)sums)[n];
  float a0 = 0.f, a1 = 0.f, a2 = 0.f, a3 = 0.f;
  int j = beg;
  for (; j + 3 < end; j += 4) {
#define LDS4(i)                                                              \
    const int2 r##i = recA[j + i];                                           \
    const float4 e##i = ((const float4*)esx)[j + i];                         \
    const float4 so##i = ((const float4*)sums)[r##i.y & 0x3FFFFFFF];         \
    const __hip_bfloat16* p##i = proj0 + (size_t)r##i.x * 256 + lane;        \
    const float q##i##0 = bf2f(p##i[0]), q##i##1 = bf2f(p##i[64]);           \
    const float q##i##2 = bf2f(p##i[128]), q##i##3 = bf2f(p##i[192]);
    LDS4(0) LDS4(1) LDS4(2) LDS4(3)
#undef LDS4
#define ACC4(i)                                                              \
    a0 = fmaf(q##i##0, e##i.x * __builtin_amdgcn_rcpf(sn.x + so##i.x + 1e-16f), a0); \
    a1 = fmaf(q##i##1, e##i.y * __builtin_amdgcn_rcpf(sn.y + so##i.y + 1e-16f), a1); \
    a2 = fmaf(q##i##2, e##i.z * __builtin_amdgcn_rcpf(sn.z + so##i.z + 1e-16f), a2); \
    a3 = fmaf(q##i##3, e##i.w * __builtin_amdgcn_rcpf(sn.w + so##i.w + 1e-16f), a3);
    ACC4(0) ACC4(1) ACC4(2) ACC4(3)
#undef ACC4
  }
  for (; j < end; ++j) {
    const int2 rA = recA[j];
    const float4 eA = ((const float4*)esx)[j];
    const float4 soA = ((const float4*)sums)[rA.y & 0x3FFFFFFF];
    const __hip_bfloat16* pA = proj0 + (size_t)rA.x * 256 + lane;
    a0 = fmaf(bf2f(pA[0]), eA.x * __builtin_amdgcn_rcpf(sn.x + soA.x + 1e-16f), a0);
    a1 = fmaf(bf2f(pA[64]), eA.y * __builtin_amdgcn_rcpf(sn.y + soA.y + 1e-16f), a1);
    a2 = fmaf(bf2f(pA[128]), eA.z * __builtin_amdgcn_rcpf(sn.z + soA.z + 1e-16f), a2);
    a3 = fmaf(bf2f(pA[192]), eA.w * __builtin_amdgcn_rcpf(sn.w + soA.w + 1e-16f), a3);
  }
  const float xs = x[(size_t)n * 64 + lane];
  float v0 = a0 + xs + b0[lane];
  float v1 = a1 + xs + b0[64 + lane];
  float v2 = a2 + xs + b0[128 + lane];
  float v3 = a3 + xs + b0[192 + lane];
  v0 = v0 > 0.f ? v0 : expm1f(v0);
  v1 = v1 > 0.f ? v1 : expm1f(v1);
  v2 = v2 > 0.f ? v2 : expm1f(v2);
  v3 = v3 > 0.f ? v3 : expm1f(v3);
  __hip_bfloat16* orow = out0b + (size_t)n * 256 + lane;
  orow[0] = __float2bfloat16(v0);
  orow[64] = __float2bfloat16(v1);
  orow[128] = __float2bfloat16(v2);
  orow[192] = __float2bfloat16(v3);
}

// ====== Layer-1 MFMA GEMM: [N,256] x [256,144] ================================
#define LDA1 264
__global__ __launch_bounds__(256) void k_mm1(
    const __hip_bfloat16* __restrict__ hsrc, const short* __restrict__ B1,
    const float* __restrict__ b1, __hip_bfloat16* __restrict__ proj1,
    float* __restrict__ out, float* __restrict__ s1, float* __restrict__ s2,
    float* __restrict__ s3) {
  __shared__ short As[64 * LDA1];
  const int t = threadIdx.x;
  const int lane = t & 63, w = t >> 6;
  const int base = blockIdx.x * 64;
  for (int q = 0; q < 8; ++q) {
    const int i = q * 256 + t;
    const int r = i >> 5;
    const int c = (i & 31) * 8;
    int rg = base + r;
    if (rg >= NNODES) rg = NNODES - 1;
    const float4 v = *(const float4*)((const short*)hsrc + (size_t)rg * 256 + c);
    *(float4*)(&As[r * LDA1 + c]) = v;
  }
  __syncthreads();
  const short8* B8 = (const short8*)B1;
  f32x4 acc[9];
#pragma unroll
  for (int g = 0; g < 9; ++g) acc[g] = (f32x4){0.f, 0.f, 0.f, 0.f};
  const int aoff = (w * 16 + (lane & 15)) * LDA1 + (lane >> 4) * 8;
#pragma unroll
  for (int s = 0; s < 8; ++s) {
    const short8 af = *(const short8*)(&As[aoff + s * 32]);
#pragma unroll
    for (int g = 0; g < 9; ++g) {
      const short8 bf = B8[(g * 8 + s) * 64 + lane];
      acc[g] = __builtin_amdgcn_mfma_f32_16x16x32_bf16(af, bf, acc[g], 0, 0, 0);
    }
  }
  const int r0 = base + w * 16 + (lane >> 4) * 4;
  const int cn = lane & 15;
#pragma unroll
  for (int g = 0; g < 4; ++g) {
    const int col = g * 16 + cn;
#pragma unroll
    for (int r = 0; r < 4; ++r) {
      const int row = r0 + r;
      if (row < NNODES)
        proj1[(size_t)row * 64 + col] = __float2bfloat16(acc[g][r]);
    }
  }
#pragma unroll
  for (int g = 4; g < 8; ++g) {
    const int col = (g - 4) * 16 + cn;
    const float bv = b1[col];
#pragma unroll
    for (int r = 0; r < 4; ++r) {
      const int row = r0 + r;
      if (row < NNODES) out[(size_t)row * 64 + col] = acc[g][r] + bv;
    }
  }
#pragma unroll
  for (int r = 0; r < 4; ++r) {
    const int row = r0 + r;
    if (row < NNODES) {
      if (cn == 0) s1[row] = acc[8][r];
      else if (cn == 1) s2[row] = acc[8][r];
      else if (cn == 2) s3[row] = acc[8][r];
    }
  }
}

// ====== Layer-1 exp-scores per slot + denominator sums ========================
__global__ void k_sums1x(const int* __restrict__ offs, const int2* __restrict__ recA,
                         const float* __restrict__ s1, const float* __restrict__ s2,
                         const float* __restrict__ s3, float* __restrict__ es1,
                         float* __restrict__ sums) {
  const int n = blockIdx.x * 256 + threadIdx.x;
  if (n >= NNODES) return;
  const int beg = offs[n], end = offs[n + 1];
  const float s2n = s2[n], s3n = s3[n];
  float acc = 0.f;
  for (int j = beg; j < end; ++j) {
    const int2 rec = recA[j];
    const int o = rec.y & 0x3FFFFFFF;
    const int role = rec.y >> 30;
    const float ov = role ? s2[o] : s3[o];
    const float sv = role ? s3n : s2n;
    float s = s1[rec.x] + ov + sv;
    s = s > 0.f ? s : 0.2f * s;
    const float e = __expf(s);
    es1[j] = e;
    acc += e;
  }
  sums[n] = acc;
}

// ========== Layer-1 aggregate, wave per node, att on the fly ==================
__global__ __launch_bounds__(256) void k_agg1(
    const int* __restrict__ offs, const int2* __restrict__ recA,
    const float* __restrict__ es1, const float* __restrict__ sums,
    const __hip_bfloat16* __restrict__ proj1, float* __restrict__ dout) {
  const int lane = threadIdx.x & 63, wid = threadIdx.x >> 6;
  const int n = blockIdx.x * 4 + wid;
  if (n >= NNODES) return;
  const int beg = offs[n], end = offs[n + 1];
  const float sn = sums[n];
  float acc0 = 0.f, acc1 = 0.f, acc2 = 0.f, acc3 = 0.f;
  int j = beg;
  for (; j + 3 < end; j += 4) {
#define LD(i)                                                              \
    const int2 r##i = recA[j + i];                                         \
    const float e##i = es1[j + i];                                         \
    const float so##i = sums[r##i.y & 0x3FFFFFFF];                         \
    const float p##i = bf2f(proj1[(unsigned)(r##i.x * 64 + lane)]);
    LD(0) LD(1) LD(2) LD(3)
#undef LD
    acc0 = fmaf(p0, e0 * __builtin_amdgcn_rcpf(sn + so0 + 1e-16f), acc0);
    acc1 = fmaf(p1, e1 * __builtin_amdgcn_rcpf(sn + so1 + 1e-16f), acc1);
    acc2 = fmaf(p2, e2 * __builtin_amdgcn_rcpf(sn + so2 + 1e-16f), acc2);
    acc3 = fmaf(p3, e3 * __builtin_amdgcn_rcpf(sn + so3 + 1e-16f), acc3);
  }
  for (; j < end; ++j) {
    const int2 rA = recA[j];
    const float soA = sums[rA.y & 0x3FFFFFFF];
    acc0 = fmaf(bf2f(proj1[(unsigned)(rA.x * 64 + lane)]),
                es1[j] * __builtin_amdgcn_rcpf(sn + soA + 1e-16f), acc0);
  }
  dout[(size_t)n * 64 + lane] += (acc0 + acc1) + (acc2 + acc3);
}

extern "C" void kernel_launch(void* const* d_in, const int* in_sizes, int n_in,
                              void* d_out, int out_size, void* d_ws, size_t ws_size,
                              hipStream_t stream) {
  const float* x = (const float*)d_in[0];
  const int* ei = (const int*)d_in[1];
  const float* W0 = (const float*)d_in[2];
  const float* a10 = (const float*)d_in[3];
  const float* a20 = (const float*)d_in[4];
  const float* a30 = (const float*)d_in[5];
  // d_in[6] = Wskip0: unused (layer-0 skip is identity, F==DIN)
  const float* b0 = (const float*)d_in[7];
  const float* W1 = (const float*)d_in[8];
  const float* a11 = (const float*)d_in[9];
  const float* a21 = (const float*)d_in[10];
  const float* a31 = (const float*)d_in[11];
  const float* Wskip1 = (const float*)d_in[12];
  const float* b1 = (const float*)d_in[13];
  float* out = (float*)d_out;

  // ---- Workspace layout: ~135 MB ----
  __hip_bfloat16* proj0 = (__hip_bfloat16*)d_ws;       // N*256 bf16
  __hip_bfloat16* out0b = proj0 + (size_t)NNODES * 256;  // N*256 bf16 (h)
  float* s1_0 = (float*)(out0b + (size_t)NNODES * 256);  // N*4 x3
  float* s2_0 = s1_0 + (size_t)NNODES * 4;
  float* s3_0 = s2_0 + (size_t)NNODES * 4;
  float* sums0 = s3_0 + (size_t)NNODES * 4;            // N*4
  float* esx0 = sums0 + (size_t)NNODES * 4;            // 2E*4 (float4/slot)
  int2* recA = (int2*)(esx0 + (size_t)2 * NEDGES * 4); // 2E int2
  int* offs = (int*)(recA + 2 * NEDGES);               // N+16
  float* s1_1 = (float*)(offs + NNODES + 16);          // N x3
  float* s2_1 = s1_1 + NNODES;
  float* s3_1 = s2_1 + NNODES;
  float* sums1 = s3_1 + NNODES;                        // N
  __hip_bfloat16* B0swz = (__hip_bfloat16*)(sums1 + NNODES);  // 17408 bf16
  __hip_bfloat16* B1swz = B0swz + 17408;               // 36864 bf16
  // CSR-build int scratch aliases esx0 (dead until k_sums0x):
  int* deg = (int*)esx0;
  int* cursor = deg + NNODES;
  int* bsums = cursor + NNODES;

  __hip_bfloat16* proj1 = proj0;  // aliases proj0 (dead after k_agg0w)
  float* es1 = esx0;              // layer-1 exp slots (esx0 dead after k_agg0w)

  // ---- weight prep (independent) ----
  k_prep0<<<68, 256, 0, stream>>>(W0, a10, a20, a30, B0swz);
  k_prepw1<<<144, 256, 0, stream>>>(W1, Wskip1, a11, a21, a31, B1swz);

  // ---- Layer-0 projection + scores via MFMA ----
  k_mm0<<<(NNODES + 63) / 64, 256, 0, stream>>>(x, (const short*)B0swz, proj0,
                                                s1_0, s2_0, s3_0);

  // ---- CSR build (packed records) ----
  hipMemsetAsync(deg, 0, NNODES * sizeof(int), stream);
  k_deg<<<(2 * NEDGES + 255) / 256, 256, 0, stream>>>(ei, deg);
  k_scan1<<<NB_SCAN, 256, 0, stream>>>(deg, offs, bsums);
  k_scan2<<<1, 512, 0, stream>>>(bsums);
  k_scan3<<<NB_SCAN, 256, 0, stream>>>(offs, bsums, cursor);
  k_fill3<<<(2 * NEDGES + 255) / 256, 256, 0, stream>>>(ei, cursor, recA);

  // ---- Layer 0: slot exp-scores + sums -> aggregate (att inline) ----
  k_sums0x<<<NB_SCAN, 256, 0, stream>>>(offs, recA, s1_0, s2_0, s3_0, esx0,
                                        sums0);
  k_agg0w<<<(NNODES + 3) / 4, 256, 0, stream>>>(offs, recA, esx0, sums0, proj0,
                                                x, b0, out0b);

  // ---- Layer 1: MFMA GEMM -> slot exp-scores + sums -> aggregate ----
  k_mm1<<<(NNODES + 63) / 64, 256, 0, stream>>>(out0b, (const short*)B1swz, b1,
                                                proj1, out, s1_1, s2_1, s3_1);
  k_sums1x<<<NB_SCAN, 256, 0, stream>>>(offs, recA, s1_1, s2_1, s3_1, es1,
                                        sums1);
  k_agg1<<<(NNODES + 3) / 4, 256, 0, stream>>>(offs, recA, es1, sums1, proj1,
                                               out);
}

// Round 10
// 546.409 us; speedup vs baseline: 1.0892x; 1.0053x over previous
//
#include <hip/hip_runtime.h>
#include <hip/hip_bf16.h>
#include <math.h>

#define NNODES 100000
#define NEDGES 500000
#define NB_SCAN 391  // ceil(NNODES/256)

typedef __attribute__((ext_vector_type(8))) short short8;
typedef __attribute__((ext_vector_type(4))) float f32x4;

__device__ __forceinline__ float bf2f(__hip_bfloat16 v) {
  return __bfloat162float(v);
}
__device__ __forceinline__ unsigned short f2b(float f) {
  __hip_bfloat16 h = __float2bfloat16(f);
  return *(unsigned short*)&h;
}
__device__ __forceinline__ float bits2f_lo(unsigned u) {
  return __uint_as_float(u << 16);
}
__device__ __forceinline__ float bits2f_hi(unsigned u) {
  return __uint_as_float(u & 0xffff0000u);
}

// ================= CSR build ==================================================
__global__ void k_deg(const int* __restrict__ ei, int* __restrict__ deg) {
  const int idx = blockIdx.x * 256 + threadIdx.x;
  if (idx < 2 * NEDGES) atomicAdd(&deg[ei[NEDGES + idx]], 1);
}

__global__ void k_scan1(const int* __restrict__ deg, int* __restrict__ offs,
                        int* __restrict__ bsums) {
  __shared__ int sh[256];
  const int t = threadIdx.x;
  const int i = blockIdx.x * 256 + t;
  const int v = (i < NNODES) ? deg[i] : 0;
  sh[t] = v;
  __syncthreads();
  for (int d = 1; d < 256; d <<= 1) {
    const int add = (t >= d) ? sh[t - d] : 0;
    __syncthreads();
    sh[t] += add;
    __syncthreads();
  }
  if (i < NNODES) offs[i] = sh[t] - v;  // exclusive
  if (t == 255) bsums[blockIdx.x] = sh[255];
}

__global__ void k_scan2(int* __restrict__ bsums) {
  __shared__ int sh[512];
  const int t = threadIdx.x;
  const int v = (t < NB_SCAN) ? bsums[t] : 0;
  sh[t] = v;
  __syncthreads();
  for (int d = 1; d < 512; d <<= 1) {
    const int add = (t >= d) ? sh[t - d] : 0;
    __syncthreads();
    sh[t] += add;
    __syncthreads();
  }
  if (t < NB_SCAN) bsums[t] = sh[t] - v;  // exclusive
}

__global__ void k_scan3(int* __restrict__ offs, const int* __restrict__ bsums,
                        int* __restrict__ cursor) {
  const int i = blockIdx.x * 256 + threadIdx.x;
  if (i < NNODES) {
    const int o = offs[i] + bsums[blockIdx.x];
    offs[i] = o;
    cursor[i] = o;
  }
  if (i == 0) offs[NNODES] = 2 * NEDGES;
}

// Fill packed slot records: (drug, other | role<<30).
__global__ void k_fill3(const int* __restrict__ ei, int* __restrict__ cursor,
                        int2* __restrict__ recA) {
  const int idx = blockIdx.x * 256 + threadIdx.x;
  if (idx >= 2 * NEDGES) return;
  const int n = ei[NEDGES + idx];
  const int e = (idx < NEDGES) ? idx : idx - NEDGES;
  const int drug = ei[e];
  const int other = (idx < NEDGES) ? ei[2 * NEDGES + e] : ei[NEDGES + e];
  const int role = (idx < NEDGES) ? 0 : 1;
  const int pos = atomicAdd(&cursor[n], 1);
  recA[pos] = make_int2(drug, other | (role << 30));
}

// ========== B-matrix prep for layer-0 MFMA GEMM (K=64, 272 cols) ==============
__global__ void k_prep0(const float* __restrict__ W0, const float* __restrict__ a1,
                        const float* __restrict__ a2, const float* __restrict__ a3,
                        __hip_bfloat16* __restrict__ B0) {
  const int t = blockIdx.x * 256 + threadIdx.x;  // < 17408
  const int j = t & 7, l = (t >> 3) & 63, s = (t >> 9) & 1, g = t >> 10;
  const int k = s * 32 + ((l >> 4) << 3) + j;
  const int col = g * 16 + (l & 15);
  float v = 0.f;
  if (col < 256) {
    v = W0[col * 64 + k];
  } else if (col < 268) {
    const int idx = col - 256;
    const int r = idx >> 2, h = idx & 3;
    const float* av = (r == 0) ? a1 : (r == 1) ? a2 : a3;
    for (int f = 0; f < 64; ++f)
      v = fmaf(av[h * 64 + f], W0[(h * 64 + f) * 64 + k], v);
  }
  B0[t] = __float2bfloat16(v);
}

// ========== B-matrix prep for layer-1 MFMA GEMM (K=256 permuted, 144 cols) ====
// A-tile k-order is head-interleaved: tile row k' holds original k=(k'&3)*64+(k'>>2).
__global__ void k_prepw1(const float* __restrict__ W1,
                         const float* __restrict__ Wskip1,
                         const float* __restrict__ a1, const float* __restrict__ a2,
                         const float* __restrict__ a3,
                         __hip_bfloat16* __restrict__ B1) {
  const int t = blockIdx.x * 256 + threadIdx.x;  // < 36864
  const int j = t & 7, l = (t >> 3) & 63, s = (t >> 9) & 7, g = t >> 12;
  const int kp = s * 32 + ((l >> 4) << 3) + j;
  const int k = (kp & 3) * 64 + (kp >> 2);  // permuted -> original
  const int col = g * 16 + (l & 15);
  float v = 0.f;
  if (col < 64) {
    v = W1[col * 256 + k];
  } else if (col < 128) {
    v = Wskip1[(col - 64) * 256 + k];
  } else if (col < 131) {
    const int r = col - 128;
    const float* av = (r == 0) ? a1 : (r == 1) ? a2 : a3;
    for (int f = 0; f < 64; ++f) v = fmaf(av[f], W1[f * 256 + k], v);
  }
  B1[t] = __float2bfloat16(v);
}

// ================= Layer-0 MFMA GEMM: [N,64] x [64,272] =======================
// proj0 stored HEAD-INTERLEAVED: proj0[n*256 + f*4 + h]  (f=0..63, h=0..3).
#define LDA0 72
__global__ __launch_bounds__(256) void k_mm0(
    const float* __restrict__ x, const short* __restrict__ B0,
    __hip_bfloat16* __restrict__ proj0, float* __restrict__ s1,
    float* __restrict__ s2, float* __restrict__ s3) {
  __shared__ __hip_bfloat16 As[64 * LDA0];
  const int t = threadIdx.x;
  const int lane = t & 63, w = t >> 6;
  const int base = blockIdx.x * 64;
  for (int q = 0; q < 4; ++q) {
    const int i = q * 256 + t;
    const int r = i >> 4;
    const int c4 = i & 15;
    int rg = base + r;
    if (rg >= NNODES) rg = NNODES - 1;
    const float4 v = ((const float4*)(x + (size_t)rg * 64))[c4];
    __hip_bfloat16* dst = &As[r * LDA0 + c4 * 4];
    dst[0] = __float2bfloat16(v.x);
    dst[1] = __float2bfloat16(v.y);
    dst[2] = __float2bfloat16(v.z);
    dst[3] = __float2bfloat16(v.w);
  }
  __syncthreads();
  const short8* B8 = (const short8*)B0;
  f32x4 acc[17];
#pragma unroll
  for (int g = 0; g < 17; ++g) acc[g] = (f32x4){0.f, 0.f, 0.f, 0.f};
  const int aoff = (w * 16 + (lane & 15)) * LDA0 + (lane >> 4) * 8;
#pragma unroll
  for (int s = 0; s < 2; ++s) {
    const short8 af = *(const short8*)(&As[aoff + s * 32]);
#pragma unroll
    for (int g = 0; g < 17; ++g) {
      const short8 bf = B8[(g * 2 + s) * 64 + lane];
      acc[g] = __builtin_amdgcn_mfma_f32_16x16x32_bf16(af, bf, acc[g], 0, 0, 0);
    }
  }
  const int r0 = base + w * 16 + (lane >> 4) * 4;
  const int cn = lane & 15;
#pragma unroll
  for (int g = 0; g < 16; ++g) {
    const int col = g * 16 + cn;
    const int idx = (col & 63) * 4 + (col >> 6);  // head-interleaved
#pragma unroll
    for (int r = 0; r < 4; ++r) {
      const int row = r0 + r;
      if (row < NNODES)
        proj0[(size_t)row * 256 + idx] = __float2bfloat16(acc[g][r]);
    }
  }
#pragma unroll
  for (int r = 0; r < 4; ++r) {
    const int row = r0 + r;
    if (row < NNODES) {
      if (cn < 4) s1[row * 4 + cn] = acc[16][r];
      else if (cn < 8) s2[row * 4 + (cn - 4)] = acc[16][r];
      else if (cn < 12) s3[row * 4 + (cn - 8)] = acc[16][r];
    }
  }
}

// ====== Layer-0 exp-scores + sums, per (node,head) — 4x TLP ===================
__global__ void k_sums0h(const int* __restrict__ offs, const int2* __restrict__ recA,
                         const float* __restrict__ s1, const float* __restrict__ s2,
                         const float* __restrict__ s3, float* __restrict__ esx,
                         float* __restrict__ sums) {
  const int idx = blockIdx.x * 256 + threadIdx.x;
  if (idx >= NNODES * 4) return;
  const int n = idx >> 2, h = idx & 3;
  const int beg = offs[n], end = offs[n + 1];
  const float s2n = s2[n * 4 + h], s3n = s3[n * 4 + h];
  float acc = 0.f;
  for (int j = beg; j < end; ++j) {
    const int2 rec = recA[j];  // quad-shared, L1 broadcast
    const int o = rec.y & 0x3FFFFFFF;
    const int role = rec.y >> 30;
    const float A = s1[rec.x * 4 + h];
    const float O = role ? s2[o * 4 + h] : s3[o * 4 + h];
    const float S = role ? s3n : s2n;
    float s = A + O + S;
    s = s > 0.f ? s : 0.2f * s;
    const float e = __expf(s);
    esx[j * 4 + h] = e;
    acc += e;
  }
  sums[idx] = acc;
}

// ====== Layer-0 attention in place, per (node,head) ===========================
__global__ void k_att0h(const int* __restrict__ offs, const int2* __restrict__ recA,
                        const float* __restrict__ sums, float* __restrict__ esx) {
  const int idx = blockIdx.x * 256 + threadIdx.x;
  if (idx >= NNODES * 4) return;
  const int n = idx >> 2, h = idx & 3;
  const int beg = offs[n], end = offs[n + 1];
  const float sn = sums[idx];
  for (int j = beg; j < end; ++j) {
    const int o = recA[j].y & 0x3FFFFFFF;
    const float so = sums[o * 4 + h];
    esx[j * 4 + h] *= __builtin_amdgcn_rcpf(sn + so + 1e-16f);
  }
}

// ====== Layer-0 aggregate, wave/node: 1 gather per slot, skip+bias+elu ========
// proj0 head-interleaved: one uint2 (4 bf16 = all heads at feature `lane`).
__global__ __launch_bounds__(256) void k_agg0w(
    const int* __restrict__ offs, const int2* __restrict__ recA,
    const float* __restrict__ att, const __hip_bfloat16* __restrict__ proj0,
    const float* __restrict__ x, const float* __restrict__ b0,
    __hip_bfloat16* __restrict__ out0b) {
  const int lane = threadIdx.x & 63, wid = threadIdx.x >> 6;
  const int n = blockIdx.x * 4 + wid;
  if (n >= NNODES) return;
  const int beg = offs[n], end = offs[n + 1];
  float a0 = 0.f, a1 = 0.f, a2 = 0.f, a3 = 0.f;
  int j = beg;
  for (; j + 3 < end; j += 4) {
#define LD(i)                                                                 \
    const int d##i = recA[j + i].x;                                           \
    const float4 t##i = ((const float4*)att)[j + i];                          \
    const uint2 r##i =                                                        \
        *(const uint2*)(proj0 + (size_t)d##i * 256 + lane * 4);
    LD(0) LD(1) LD(2) LD(3)
#undef LD
#define ACC(i)                                                                \
    a0 = fmaf(bits2f_lo(r##i.x), t##i.x, a0);                                 \
    a1 = fmaf(bits2f_hi(r##i.x), t##i.y, a1);                                 \
    a2 = fmaf(bits2f_lo(r##i.y), t##i.z, a2);                                 \
    a3 = fmaf(bits2f_hi(r##i.y), t##i.w, a3);
    ACC(0) ACC(1) ACC(2) ACC(3)
#undef ACC
  }
  for (; j < end; ++j) {
    const int d0 = recA[j].x;
    const float4 t0 = ((const float4*)att)[j];
    const uint2 r0 = *(const uint2*)(proj0 + (size_t)d0 * 256 + lane * 4);
    a0 = fmaf(bits2f_lo(r0.x), t0.x, a0);
    a1 = fmaf(bits2f_hi(r0.x), t0.y, a1);
    a2 = fmaf(bits2f_lo(r0.y), t0.z, a2);
    a3 = fmaf(bits2f_hi(r0.y), t0.w, a3);
  }
  const float xs = x[(size_t)n * 64 + lane];
  float v0 = a0 + xs + b0[lane];
  float v1 = a1 + xs + b0[64 + lane];
  float v2 = a2 + xs + b0[128 + lane];
  float v3 = a3 + xs + b0[192 + lane];
  v0 = v0 > 0.f ? v0 : expm1f(v0);
  v1 = v1 > 0.f ? v1 : expm1f(v1);
  v2 = v2 > 0.f ? v2 : expm1f(v2);
  v3 = v3 > 0.f ? v3 : expm1f(v3);
  uint2 o;
  o.x = (unsigned)f2b(v0) | ((unsigned)f2b(v1) << 16);
  o.y = (unsigned)f2b(v2) | ((unsigned)f2b(v3) << 16);
  *(uint2*)(out0b + (size_t)n * 256 + lane * 4) = o;  // coalesced 8B store
}

// ====== Layer-1 MFMA GEMM: [N,256] x [256,144] (k-permuted B) =================
#define LDA1 264
__global__ __launch_bounds__(256) void k_mm1(
    const __hip_bfloat16* __restrict__ hsrc, const short* __restrict__ B1,
    const float* __restrict__ b1, __hip_bfloat16* __restrict__ proj1,
    float* __restrict__ out, float* __restrict__ s1, float* __restrict__ s2,
    float* __restrict__ s3) {
  __shared__ short As[64 * LDA1];
  const int t = threadIdx.x;
  const int lane = t & 63, w = t >> 6;
  const int base = blockIdx.x * 64;
  for (int q = 0; q < 8; ++q) {
    const int i = q * 256 + t;
    const int r = i >> 5;
    const int c = (i & 31) * 8;
    int rg = base + r;
    if (rg >= NNODES) rg = NNODES - 1;
    const float4 v = *(const float4*)((const short*)hsrc + (size_t)rg * 256 + c);
    *(float4*)(&As[r * LDA1 + c]) = v;
  }
  __syncthreads();
  const short8* B8 = (const short8*)B1;
  f32x4 acc[9];
#pragma unroll
  for (int g = 0; g < 9; ++g) acc[g] = (f32x4){0.f, 0.f, 0.f, 0.f};
  const int aoff = (w * 16 + (lane & 15)) * LDA1 + (lane >> 4) * 8;
#pragma unroll
  for (int s = 0; s < 8; ++s) {
    const short8 af = *(const short8*)(&As[aoff + s * 32]);
#pragma unroll
    for (int g = 0; g < 9; ++g) {
      const short8 bf = B8[(g * 8 + s) * 64 + lane];
      acc[g] = __builtin_amdgcn_mfma_f32_16x16x32_bf16(af, bf, acc[g], 0, 0, 0);
    }
  }
  const int r0 = base + w * 16 + (lane >> 4) * 4;
  const int cn = lane & 15;
#pragma unroll
  for (int g = 0; g < 4; ++g) {
    const int col = g * 16 + cn;
#pragma unroll
    for (int r = 0; r < 4; ++r) {
      const int row = r0 + r;
      if (row < NNODES)
        proj1[(size_t)row * 64 + col] = __float2bfloat16(acc[g][r]);
    }
  }
#pragma unroll
  for (int g = 4; g < 8; ++g) {
    const int col = (g - 4) * 16 + cn;
    const float bv = b1[col];
#pragma unroll
    for (int r = 0; r < 4; ++r) {
      const int row = r0 + r;
      if (row < NNODES) out[(size_t)row * 64 + col] = acc[g][r] + bv;
    }
  }
#pragma unroll
  for (int r = 0; r < 4; ++r) {
    const int row = r0 + r;
    if (row < NNODES) {
      if (cn == 0) s1[row] = acc[8][r];
      else if (cn == 1) s2[row] = acc[8][r];
      else if (cn == 2) s3[row] = acc[8][r];
    }
  }
}

// ====== Layer-1 exp-scores per slot + denominator sums ========================
__global__ void k_sums1x(const int* __restrict__ offs, const int2* __restrict__ recA,
                         const float* __restrict__ s1, const float* __restrict__ s2,
                         const float* __restrict__ s3, float* __restrict__ es1,
                         float* __restrict__ sums) {
  const int n = blockIdx.x * 256 + threadIdx.x;
  if (n >= NNODES) return;
  const int beg = offs[n], end = offs[n + 1];
  const float s2n = s2[n], s3n = s3[n];
  float acc = 0.f;
  for (int j = beg; j < end; ++j) {
    const int2 rec = recA[j];
    const int o = rec.y & 0x3FFFFFFF;
    const int role = rec.y >> 30;
    const float ov = role ? s2[o] : s3[o];
    const float sv = role ? s3n : s2n;
    float s = s1[rec.x] + ov + sv;
    s = s > 0.f ? s : 0.2f * s;
    const float e = __expf(s);
    es1[j] = e;
    acc += e;
  }
  sums[n] = acc;
}

// ========== Layer-1 aggregate, wave per node, att on the fly ==================
__global__ __launch_bounds__(256) void k_agg1(
    const int* __restrict__ offs, const int2* __restrict__ recA,
    const float* __restrict__ es1, const float* __restrict__ sums,
    const __hip_bfloat16* __restrict__ proj1, float* __restrict__ dout) {
  const int lane = threadIdx.x & 63, wid = threadIdx.x >> 6;
  const int n = blockIdx.x * 4 + wid;
  if (n >= NNODES) return;
  const int beg = offs[n], end = offs[n + 1];
  const float sn = sums[n];
  float acc0 = 0.f, acc1 = 0.f, acc2 = 0.f, acc3 = 0.f;
  int j = beg;
  for (; j + 3 < end; j += 4) {
#define LD(i)                                                              \
    const int2 r##i = recA[j + i];                                         \
    const float e##i = es1[j + i];                                         \
    const float so##i = sums[r##i.y & 0x3FFFFFFF];                         \
    const float p##i = bf2f(proj1[(unsigned)(r##i.x * 64 + lane)]);
    LD(0) LD(1) LD(2) LD(3)
#undef LD
    acc0 = fmaf(p0, e0 * __builtin_amdgcn_rcpf(sn + so0 + 1e-16f), acc0);
    acc1 = fmaf(p1, e1 * __builtin_amdgcn_rcpf(sn + so1 + 1e-16f), acc1);
    acc2 = fmaf(p2, e2 * __builtin_amdgcn_rcpf(sn + so2 + 1e-16f), acc2);
    acc3 = fmaf(p3, e3 * __builtin_amdgcn_rcpf(sn + so3 + 1e-16f), acc3);
  }
  for (; j < end; ++j) {
    const int2 rA = recA[j];
    const float soA = sums[rA.y & 0x3FFFFFFF];
    acc0 = fmaf(bf2f(proj1[(unsigned)(rA.x * 64 + lane)]),
                es1[j] * __builtin_amdgcn_rcpf(sn + soA + 1e-16f), acc0);
  }
  dout[(size_t)n * 64 + lane] += (acc0 + acc1) + (acc2 + acc3);
}

extern "C" void kernel_launch(void* const* d_in, const int* in_sizes, int n_in,
                              void* d_out, int out_size, void* d_ws, size_t ws_size,
                              hipStream_t stream) {
  const float* x = (const float*)d_in[0];
  const int* ei = (const int*)d_in[1];
  const float* W0 = (const float*)d_in[2];
  const float* a10 = (const float*)d_in[3];
  const float* a20 = (const float*)d_in[4];
  const float* a30 = (const float*)d_in[5];
  // d_in[6] = Wskip0: unused (layer-0 skip is identity, F==DIN)
  const float* b0 = (const float*)d_in[7];
  const float* W1 = (const float*)d_in[8];
  const float* a11 = (const float*)d_in[9];
  const float* a21 = (const float*)d_in[10];
  const float* a31 = (const float*)d_in[11];
  const float* Wskip1 = (const float*)d_in[12];
  const float* b1 = (const float*)d_in[13];
  float* out = (float*)d_out;

  // ---- Workspace layout: ~135 MB ----
  __hip_bfloat16* proj0 = (__hip_bfloat16*)d_ws;       // N*256 bf16 (head-ilv)
  __hip_bfloat16* out0b = proj0 + (size_t)NNODES * 256;  // N*256 bf16 (head-ilv)
  float* s1_0 = (float*)(out0b + (size_t)NNODES * 256);  // N*4 x3
  float* s2_0 = s1_0 + (size_t)NNODES * 4;
  float* s3_0 = s2_0 + (size_t)NNODES * 4;
  float* sums0 = s3_0 + (size_t)NNODES * 4;            // N*4
  float* esx0 = sums0 + (size_t)NNODES * 4;            // 2E*4
  int2* recA = (int2*)(esx0 + (size_t)2 * NEDGES * 4); // 2E int2
  int* offs = (int*)(recA + 2 * NEDGES);               // N+16
  float* s1_1 = (float*)(offs + NNODES + 16);          // N x3
  float* s2_1 = s1_1 + NNODES;
  float* s3_1 = s2_1 + NNODES;
  float* sums1 = s3_1 + NNODES;                        // N
  __hip_bfloat16* B0swz = (__hip_bfloat16*)(sums1 + NNODES);  // 17408 bf16
  __hip_bfloat16* B1swz = B0swz + 17408;               // 36864 bf16
  // CSR-build int scratch aliases esx0 (dead until k_sums0h):
  int* deg = (int*)esx0;
  int* cursor = deg + NNODES;
  int* bsums = cursor + NNODES;

  __hip_bfloat16* proj1 = proj0;  // aliases proj0 (dead after k_agg0w)
  float* es1 = esx0;              // layer-1 exp slots (esx0 dead after k_agg0w)

  // ---- weight prep (independent) ----
  k_prep0<<<68, 256, 0, stream>>>(W0, a10, a20, a30, B0swz);
  k_prepw1<<<144, 256, 0, stream>>>(W1, Wskip1, a11, a21, a31, B1swz);

  // ---- Layer-0 projection + scores via MFMA ----
  k_mm0<<<(NNODES + 63) / 64, 256, 0, stream>>>(x, (const short*)B0swz, proj0,
                                                s1_0, s2_0, s3_0);

  // ---- CSR build (packed records) ----
  hipMemsetAsync(deg, 0, NNODES * sizeof(int), stream);
  k_deg<<<(2 * NEDGES + 255) / 256, 256, 0, stream>>>(ei, deg);
  k_scan1<<<NB_SCAN, 256, 0, stream>>>(deg, offs, bsums);
  k_scan2<<<1, 512, 0, stream>>>(bsums);
  k_scan3<<<NB_SCAN, 256, 0, stream>>>(offs, bsums, cursor);
  k_fill3<<<(2 * NEDGES + 255) / 256, 256, 0, stream>>>(ei, cursor, recA);

  // ---- Layer 0: (node,head) exp+sums -> att -> aggregate ----
  k_sums0h<<<(NNODES * 4 + 255) / 256, 256, 0, stream>>>(offs, recA, s1_0, s2_0,
                                                         s3_0, esx0, sums0);
  k_att0h<<<(NNODES * 4 + 255) / 256, 256, 0, stream>>>(offs, recA, sums0, esx0);
  k_agg0w<<<(NNODES + 3) / 4, 256, 0, stream>>>(offs, recA, esx0, proj0, x, b0,
                                                out0b);

  // ---- Layer 1: MFMA GEMM -> slot exp+sums -> aggregate (att inline) ----
  k_mm1<<<(NNODES + 63) / 64, 256, 0, stream>>>(out0b, (const short*)B1swz, b1,
                                                proj1, out, s1_1, s2_1, s3_1);
  k_sums1x<<<NB_SCAN, 256, 0, stream>>>(offs, recA, s1_1, s2_1, s3_1, es1,
                                        sums1);
  k_agg1<<<(NNODES + 3) / 4, 256, 0, stream>>>(offs, recA, es1, sums1, proj1,
                                               out);
}

// Round 11
// 487.399 us; speedup vs baseline: 1.2211x; 1.1211x over previous
//
#include <hip/hip_runtime.h>
#include <hip/hip_bf16.h>
#include <math.h>

#define NNODES 100000
#define NEDGES 500000
#define NB_SCAN 391  // ceil(NNODES/256)

typedef __attribute__((ext_vector_type(8))) short short8;
typedef __attribute__((ext_vector_type(4))) float f32x4;

__device__ __forceinline__ float bf2f(__hip_bfloat16 v) {
  return __bfloat162float(v);
}
__device__ __forceinline__ unsigned short f2b(float f) {
  __hip_bfloat16 h = __float2bfloat16(f);
  return *(unsigned short*)&h;
}
__device__ __forceinline__ float bits2f_lo(unsigned u) {
  return __uint_as_float(u << 16);
}
__device__ __forceinline__ float bits2f_hi(unsigned u) {
  return __uint_as_float(u & 0xffff0000u);
}

// ================= CSR build ==================================================
__global__ void k_deg(const int* __restrict__ ei, int* __restrict__ deg) {
  const int idx = blockIdx.x * 256 + threadIdx.x;
  if (idx < 2 * NEDGES) atomicAdd(&deg[ei[NEDGES + idx]], 1);
}

__global__ void k_scan1(const int* __restrict__ deg, int* __restrict__ offs,
                        int* __restrict__ bsums) {
  __shared__ int sh[256];
  const int t = threadIdx.x;
  const int i = blockIdx.x * 256 + t;
  const int v = (i < NNODES) ? deg[i] : 0;
  sh[t] = v;
  __syncthreads();
  for (int d = 1; d < 256; d <<= 1) {
    const int add = (t >= d) ? sh[t - d] : 0;
    __syncthreads();
    sh[t] += add;
    __syncthreads();
  }
  if (i < NNODES) offs[i] = sh[t] - v;  // exclusive
  if (t == 255) bsums[blockIdx.x] = sh[255];
}

__global__ void k_scan2(int* __restrict__ bsums) {
  __shared__ int sh[512];
  const int t = threadIdx.x;
  const int v = (t < NB_SCAN) ? bsums[t] : 0;
  sh[t] = v;
  __syncthreads();
  for (int d = 1; d < 512; d <<= 1) {
    const int add = (t >= d) ? sh[t - d] : 0;
    __syncthreads();
    sh[t] += add;
    __syncthreads();
  }
  if (t < NB_SCAN) bsums[t] = sh[t] - v;  // exclusive
}

__global__ void k_scan3(int* __restrict__ offs, const int* __restrict__ bsums,
                        int* __restrict__ cursor) {
  const int i = blockIdx.x * 256 + threadIdx.x;
  if (i < NNODES) {
    const int o = offs[i] + bsums[blockIdx.x];
    offs[i] = o;
    cursor[i] = o;
  }
  if (i == 0) offs[NNODES] = 2 * NEDGES;
}

// Fill slot records: recA=(drug, other|role<<30), rcvA=receiver node.
__global__ void k_fill3(const int* __restrict__ ei, int* __restrict__ cursor,
                        int2* __restrict__ recA, int* __restrict__ rcvA) {
  const int idx = blockIdx.x * 256 + threadIdx.x;
  if (idx >= 2 * NEDGES) return;
  const int n = ei[NEDGES + idx];
  const int e = (idx < NEDGES) ? idx : idx - NEDGES;
  const int drug = ei[e];
  const int other = (idx < NEDGES) ? ei[2 * NEDGES + e] : ei[NEDGES + e];
  const int role = (idx < NEDGES) ? 0 : 1;
  const int pos = atomicAdd(&cursor[n], 1);
  recA[pos] = make_int2(drug, other | (role << 30));
  rcvA[pos] = n;
}

// ========== Fused B-matrix prep: blocks 0..67 -> B0 (layer 0), rest -> B1 =====
__global__ void k_prep(const float* __restrict__ W0, const float* __restrict__ a10,
                       const float* __restrict__ a20, const float* __restrict__ a30,
                       const float* __restrict__ W1, const float* __restrict__ Wsk,
                       const float* __restrict__ a11, const float* __restrict__ a21,
                       const float* __restrict__ a31,
                       __hip_bfloat16* __restrict__ B0,
                       __hip_bfloat16* __restrict__ B1) {
  if (blockIdx.x < 68) {
    const int t = blockIdx.x * 256 + threadIdx.x;  // < 17408
    const int j = t & 7, l = (t >> 3) & 63, s = (t >> 9) & 1, g = t >> 10;
    const int k = s * 32 + ((l >> 4) << 3) + j;
    const int col = g * 16 + (l & 15);
    float v = 0.f;
    if (col < 256) {
      v = W0[col * 64 + k];
    } else if (col < 268) {
      const int idx = col - 256;
      const int r = idx >> 2, h = idx & 3;
      const float* av = (r == 0) ? a10 : (r == 1) ? a20 : a30;
      for (int f = 0; f < 64; ++f)
        v = fmaf(av[h * 64 + f], W0[(h * 64 + f) * 64 + k], v);
    }
    B0[t] = __float2bfloat16(v);
  } else {
    const int t = (blockIdx.x - 68) * 256 + threadIdx.x;  // < 36864
    const int j = t & 7, l = (t >> 3) & 63, s = (t >> 9) & 7, g = t >> 12;
    const int kp = s * 32 + ((l >> 4) << 3) + j;
    const int k = (kp & 3) * 64 + (kp >> 2);  // permuted -> original (head-ilv A)
    const int col = g * 16 + (l & 15);
    float v = 0.f;
    if (col < 64) {
      v = W1[col * 256 + k];
    } else if (col < 128) {
      v = Wsk[(col - 64) * 256 + k];
    } else if (col < 131) {
      const int r = col - 128;
      const float* av = (r == 0) ? a11 : (r == 1) ? a21 : a31;
      for (int f = 0; f < 64; ++f) v = fmaf(av[f], W1[f * 256 + k], v);
    }
    B1[t] = __float2bfloat16(v);
  }
}

// ================= Layer-0 MFMA GEMM: [N,64] x [64,272] =======================
// proj0 stored HEAD-INTERLEAVED: proj0[n*256 + f*4 + h]; packed uint2 stores.
#define LDA0 72
__global__ __launch_bounds__(256) void k_mm0(
    const float* __restrict__ x, const short* __restrict__ B0,
    __hip_bfloat16* __restrict__ proj0, float* __restrict__ s1,
    float* __restrict__ s2, float* __restrict__ s3) {
  __shared__ __hip_bfloat16 As[64 * LDA0];
  const int t = threadIdx.x;
  const int lane = t & 63, w = t >> 6;
  const int base = blockIdx.x * 64;
  for (int q = 0; q < 4; ++q) {
    const int i = q * 256 + t;
    const int r = i >> 4;
    const int c4 = i & 15;
    int rg = base + r;
    if (rg >= NNODES) rg = NNODES - 1;
    const float4 v = ((const float4*)(x + (size_t)rg * 64))[c4];
    __hip_bfloat16* dst = &As[r * LDA0 + c4 * 4];
    dst[0] = __float2bfloat16(v.x);
    dst[1] = __float2bfloat16(v.y);
    dst[2] = __float2bfloat16(v.z);
    dst[3] = __float2bfloat16(v.w);
  }
  __syncthreads();
  const short8* B8 = (const short8*)B0;
  f32x4 acc[17];
#pragma unroll
  for (int g = 0; g < 17; ++g) acc[g] = (f32x4){0.f, 0.f, 0.f, 0.f};
  const int aoff = (w * 16 + (lane & 15)) * LDA0 + (lane >> 4) * 8;
#pragma unroll
  for (int s = 0; s < 2; ++s) {
    const short8 af = *(const short8*)(&As[aoff + s * 32]);
#pragma unroll
    for (int g = 0; g < 17; ++g) {
      const short8 bf = B8[(g * 2 + s) * 64 + lane];
      acc[g] = __builtin_amdgcn_mfma_f32_16x16x32_bf16(af, bf, acc[g], 0, 0, 0);
    }
  }
  const int r0 = base + w * 16 + (lane >> 4) * 4;
  const int cn = lane & 15;
  // packed epilogue: heads h of feature f=g*16+cn are acc[g+4h]
#pragma unroll
  for (int g = 0; g < 4; ++g) {
    const int f = g * 16 + cn;
#pragma unroll
    for (int r = 0; r < 4; ++r) {
      const int row = r0 + r;
      if (row < NNODES) {
        uint2 o;
        o.x = (unsigned)f2b(acc[g][r]) | ((unsigned)f2b(acc[g + 4][r]) << 16);
        o.y = (unsigned)f2b(acc[g + 8][r]) | ((unsigned)f2b(acc[g + 12][r]) << 16);
        *(uint2*)(proj0 + (size_t)row * 256 + f * 4) = o;
      }
    }
  }
#pragma unroll
  for (int r = 0; r < 4; ++r) {
    const int row = r0 + r;
    if (row < NNODES) {
      if (cn < 4) s1[row * 4 + cn] = acc[16][r];
      else if (cn < 8) s2[row * 4 + (cn - 4)] = acc[16][r];
      else if (cn < 12) s3[row * 4 + (cn - 8)] = acc[16][r];
    }
  }
}

// ====== Layer-0 exp-scores, SLOT-PARALLEL (no loops) ==========================
__global__ void k_esx0(const int2* __restrict__ recA, const int* __restrict__ rcvA,
                       const float* __restrict__ s1, const float* __restrict__ s2,
                       const float* __restrict__ s3, float* __restrict__ esx) {
  const int j = blockIdx.x * 256 + threadIdx.x;
  if (j >= 2 * NEDGES) return;
  const int2 rec = recA[j];
  const int n = rcvA[j];
  const int o = rec.y & 0x3FFFFFFF;
  const int role = rec.y >> 30;
  const float4 A = ((const float4*)s1)[rec.x];
  const float4 T = ((const float4*)s2)[role ? o : n];
  const float4 D = ((const float4*)s3)[role ? n : o];
  float4 es;
  float s;
  s = A.x + T.x + D.x; s = s > 0.f ? s : 0.2f * s; es.x = __expf(s);
  s = A.y + T.y + D.y; s = s > 0.f ? s : 0.2f * s; es.y = __expf(s);
  s = A.z + T.z + D.z; s = s > 0.f ? s : 0.2f * s; es.z = __expf(s);
  s = A.w + T.w + D.w; s = s > 0.f ? s : 0.2f * s; es.w = __expf(s);
  ((float4*)esx)[j] = es;
}

// ====== Layer-0 denominator sums: per node, sequential esx reads ==============
__global__ void k_sums0n(const int* __restrict__ offs, const float* __restrict__ esx,
                         float* __restrict__ sums) {
  const int n = blockIdx.x * 256 + threadIdx.x;
  if (n >= NNODES) return;
  const int beg = offs[n], end = offs[n + 1];
  float4 acc = make_float4(0.f, 0.f, 0.f, 0.f);
  for (int j = beg; j < end; ++j) {
    const float4 v = ((const float4*)esx)[j];
    acc.x += v.x; acc.y += v.y; acc.z += v.z; acc.w += v.w;
  }
  ((float4*)sums)[n] = acc;
}

// ====== Layer-0 attention, SLOT-PARALLEL, in place ============================
__global__ void k_att0s(const int2* __restrict__ recA, const int* __restrict__ rcvA,
                        const float* __restrict__ sums, float* __restrict__ esx) {
  const int j = blockIdx.x * 256 + threadIdx.x;
  if (j >= 2 * NEDGES) return;
  const int o = recA[j].y & 0x3FFFFFFF;
  const int n = rcvA[j];
  const float4 sn = ((const float4*)sums)[n];
  const float4 so = ((const float4*)sums)[o];
  float4 e = ((const float4*)esx)[j];
  e.x *= __builtin_amdgcn_rcpf(sn.x + so.x + 1e-16f);
  e.y *= __builtin_amdgcn_rcpf(sn.y + so.y + 1e-16f);
  e.z *= __builtin_amdgcn_rcpf(sn.z + so.z + 1e-16f);
  e.w *= __builtin_amdgcn_rcpf(sn.w + so.w + 1e-16f);
  ((float4*)esx)[j] = e;
}

// ====== Layer-0 aggregate, wave/node: 1 gather per slot, skip+bias+elu ========
__global__ __launch_bounds__(256) void k_agg0w(
    const int* __restrict__ offs, const int2* __restrict__ recA,
    const float* __restrict__ att, const __hip_bfloat16* __restrict__ proj0,
    const float* __restrict__ x, const float* __restrict__ b0,
    __hip_bfloat16* __restrict__ out0b) {
  const int lane = threadIdx.x & 63, wid = threadIdx.x >> 6;
  const int n = blockIdx.x * 4 + wid;
  if (n >= NNODES) return;
  const int beg = offs[n], end = offs[n + 1];
  float a0 = 0.f, a1 = 0.f, a2 = 0.f, a3 = 0.f;
  int j = beg;
  for (; j + 3 < end; j += 4) {
#define LD(i)                                                                 \
    const int d##i = recA[j + i].x;                                           \
    const float4 t##i = ((const float4*)att)[j + i];                          \
    const uint2 r##i =                                                        \
        *(const uint2*)(proj0 + (size_t)d##i * 256 + lane * 4);
    LD(0) LD(1) LD(2) LD(3)
#undef LD
#define ACC(i)                                                                \
    a0 = fmaf(bits2f_lo(r##i.x), t##i.x, a0);                                 \
    a1 = fmaf(bits2f_hi(r##i.x), t##i.y, a1);                                 \
    a2 = fmaf(bits2f_lo(r##i.y), t##i.z, a2);                                 \
    a3 = fmaf(bits2f_hi(r##i.y), t##i.w, a3);
    ACC(0) ACC(1) ACC(2) ACC(3)
#undef ACC
  }
  for (; j < end; ++j) {
    const int d0 = recA[j].x;
    const float4 t0 = ((const float4*)att)[j];
    const uint2 r0 = *(const uint2*)(proj0 + (size_t)d0 * 256 + lane * 4);
    a0 = fmaf(bits2f_lo(r0.x), t0.x, a0);
    a1 = fmaf(bits2f_hi(r0.x), t0.y, a1);
    a2 = fmaf(bits2f_lo(r0.y), t0.z, a2);
    a3 = fmaf(bits2f_hi(r0.y), t0.w, a3);
  }
  const float xs = x[(size_t)n * 64 + lane];
  float v0 = a0 + xs + b0[lane];
  float v1 = a1 + xs + b0[64 + lane];
  float v2 = a2 + xs + b0[128 + lane];
  float v3 = a3 + xs + b0[192 + lane];
  v0 = v0 > 0.f ? v0 : expm1f(v0);
  v1 = v1 > 0.f ? v1 : expm1f(v1);
  v2 = v2 > 0.f ? v2 : expm1f(v2);
  v3 = v3 > 0.f ? v3 : expm1f(v3);
  uint2 o;
  o.x = (unsigned)f2b(v0) | ((unsigned)f2b(v1) << 16);
  o.y = (unsigned)f2b(v2) | ((unsigned)f2b(v3) << 16);
  *(uint2*)(out0b + (size_t)n * 256 + lane * 4) = o;
}

// ====== Layer-1 MFMA GEMM: [N,256] x [256,144] (k-permuted B) =================
#define LDA1 264
__global__ __launch_bounds__(256) void k_mm1(
    const __hip_bfloat16* __restrict__ hsrc, const short* __restrict__ B1,
    const float* __restrict__ b1, __hip_bfloat16* __restrict__ proj1,
    float* __restrict__ out, float* __restrict__ s1, float* __restrict__ s2,
    float* __restrict__ s3) {
  __shared__ short As[64 * LDA1];
  const int t = threadIdx.x;
  const int lane = t & 63, w = t >> 6;
  const int base = blockIdx.x * 64;
  for (int q = 0; q < 8; ++q) {
    const int i = q * 256 + t;
    const int r = i >> 5;
    const int c = (i & 31) * 8;
    int rg = base + r;
    if (rg >= NNODES) rg = NNODES - 1;
    const float4 v = *(const float4*)((const short*)hsrc + (size_t)rg * 256 + c);
    *(float4*)(&As[r * LDA1 + c]) = v;
  }
  __syncthreads();
  const short8* B8 = (const short8*)B1;
  f32x4 acc[9];
#pragma unroll
  for (int g = 0; g < 9; ++g) acc[g] = (f32x4){0.f, 0.f, 0.f, 0.f};
  const int aoff = (w * 16 + (lane & 15)) * LDA1 + (lane >> 4) * 8;
#pragma unroll
  for (int s = 0; s < 8; ++s) {
    const short8 af = *(const short8*)(&As[aoff + s * 32]);
#pragma unroll
    for (int g = 0; g < 9; ++g) {
      const short8 bf = B8[(g * 8 + s) * 64 + lane];
      acc[g] = __builtin_amdgcn_mfma_f32_16x16x32_bf16(af, bf, acc[g], 0, 0, 0);
    }
  }
  const int r0 = base + w * 16 + (lane >> 4) * 4;
  const int cn = lane & 15;
#pragma unroll
  for (int g = 0; g < 4; ++g) {
    const int col = g * 16 + cn;
#pragma unroll
    for (int r = 0; r < 4; ++r) {
      const int row = r0 + r;
      if (row < NNODES)
        proj1[(size_t)row * 64 + col] = __float2bfloat16(acc[g][r]);
    }
  }
#pragma unroll
  for (int g = 4; g < 8; ++g) {
    const int col = (g - 4) * 16 + cn;
    const float bv = b1[col];
#pragma unroll
    for (int r = 0; r < 4; ++r) {
      const int row = r0 + r;
      if (row < NNODES) out[(size_t)row * 64 + col] = acc[g][r] + bv;
    }
  }
#pragma unroll
  for (int r = 0; r < 4; ++r) {
    const int row = r0 + r;
    if (row < NNODES) {
      if (cn == 0) s1[row] = acc[8][r];
      else if (cn == 1) s2[row] = acc[8][r];
      else if (cn == 2) s3[row] = acc[8][r];
    }
  }
}

// ====== Layer-1 exp-scores, SLOT-PARALLEL =====================================
__global__ void k_esx1(const int2* __restrict__ recA, const int* __restrict__ rcvA,
                       const float* __restrict__ s1, const float* __restrict__ s2,
                       const float* __restrict__ s3, float* __restrict__ es1) {
  const int j = blockIdx.x * 256 + threadIdx.x;
  if (j >= 2 * NEDGES) return;
  const int2 rec = recA[j];
  const int n = rcvA[j];
  const int o = rec.y & 0x3FFFFFFF;
  const int role = rec.y >> 30;
  float s = s1[rec.x] + s2[role ? o : n] + s3[role ? n : o];
  s = s > 0.f ? s : 0.2f * s;
  es1[j] = __expf(s);
}

// ====== Layer-1 denominator sums: per node, sequential ========================
__global__ void k_sums1n(const int* __restrict__ offs, const float* __restrict__ es1,
                         float* __restrict__ sums) {
  const int n = blockIdx.x * 256 + threadIdx.x;
  if (n >= NNODES) return;
  const int beg = offs[n], end = offs[n + 1];
  float acc = 0.f;
  for (int j = beg; j < end; ++j) acc += es1[j];
  sums[n] = acc;
}

// ====== Layer-1 attention, SLOT-PARALLEL, in place ============================
__global__ void k_att1s(const int2* __restrict__ recA, const int* __restrict__ rcvA,
                        const float* __restrict__ sums, float* __restrict__ es1) {
  const int j = blockIdx.x * 256 + threadIdx.x;
  if (j >= 2 * NEDGES) return;
  const int o = recA[j].y & 0x3FFFFFFF;
  const int n = rcvA[j];
  es1[j] *= __builtin_amdgcn_rcpf(sums[n] + sums[o] + 1e-16f);
}

// ========== Layer-1 aggregate, wave per node: pure gather+fma =================
__global__ __launch_bounds__(256) void k_agg1(
    const int* __restrict__ offs, const int2* __restrict__ recA,
    const float* __restrict__ att1, const __hip_bfloat16* __restrict__ proj1,
    float* __restrict__ dout) {
  const int lane = threadIdx.x & 63, wid = threadIdx.x >> 6;
  const int n = blockIdx.x * 4 + wid;
  if (n >= NNODES) return;
  const int beg = offs[n], end = offs[n + 1];
  float acc0 = 0.f, acc1 = 0.f, acc2 = 0.f, acc3 = 0.f;
  int j = beg;
  for (; j + 3 < end; j += 4) {
#define LD(i)                                                              \
    const int d##i = recA[j + i].x;                                        \
    const float a##i = att1[j + i];                                        \
    const float p##i = bf2f(proj1[(unsigned)(d##i * 64 + lane)]);
    LD(0) LD(1) LD(2) LD(3)
#undef LD
    acc0 = fmaf(p0, a0, acc0);
    acc1 = fmaf(p1, a1, acc1);
    acc2 = fmaf(p2, a2, acc2);
    acc3 = fmaf(p3, a3, acc3);
  }
  for (; j < end; ++j) {
    acc0 = fmaf(bf2f(proj1[(unsigned)(recA[j].x * 64 + lane)]), att1[j], acc0);
  }
  dout[(size_t)n * 64 + lane] += (acc0 + acc1) + (acc2 + acc3);
}

extern "C" void kernel_launch(void* const* d_in, const int* in_sizes, int n_in,
                              void* d_out, int out_size, void* d_ws, size_t ws_size,
                              hipStream_t stream) {
  const float* x = (const float*)d_in[0];
  const int* ei = (const int*)d_in[1];
  const float* W0 = (const float*)d_in[2];
  const float* a10 = (const float*)d_in[3];
  const float* a20 = (const float*)d_in[4];
  const float* a30 = (const float*)d_in[5];
  // d_in[6] = Wskip0: unused (layer-0 skip is identity, F==DIN)
  const float* b0 = (const float*)d_in[7];
  const float* W1 = (const float*)d_in[8];
  const float* a11 = (const float*)d_in[9];
  const float* a21 = (const float*)d_in[10];
  const float* a31 = (const float*)d_in[11];
  const float* Wskip1 = (const float*)d_in[12];
  const float* b1 = (const float*)d_in[13];
  float* out = (float*)d_out;

  // ---- Workspace layout: ~140 MB ----
  __hip_bfloat16* proj0 = (__hip_bfloat16*)d_ws;       // N*256 bf16 (head-ilv)
  __hip_bfloat16* out0b = proj0 + (size_t)NNODES * 256;  // N*256 bf16 (head-ilv)
  float* s1_0 = (float*)(out0b + (size_t)NNODES * 256);  // N*4 x3
  float* s2_0 = s1_0 + (size_t)NNODES * 4;
  float* s3_0 = s2_0 + (size_t)NNODES * 4;
  float* sums0 = s3_0 + (size_t)NNODES * 4;            // N*4
  float* esx0 = sums0 + (size_t)NNODES * 4;            // 2E*4
  int2* recA = (int2*)(esx0 + (size_t)2 * NEDGES * 4); // 2E int2
  int* rcvA = (int*)(recA + 2 * NEDGES);               // 2E
  int* offs = rcvA + 2 * NEDGES;                       // N+16
  float* s1_1 = (float*)(offs + NNODES + 16);          // N x3
  float* s2_1 = s1_1 + NNODES;
  float* s3_1 = s2_1 + NNODES;
  float* sums1 = s3_1 + NNODES;                        // N
  __hip_bfloat16* B0swz = (__hip_bfloat16*)(sums1 + NNODES);  // 17408 bf16
  __hip_bfloat16* B1swz = B0swz + 17408;               // 36864 bf16
  // CSR-build int scratch aliases esx0 (dead until k_esx0):
  int* deg = (int*)esx0;
  int* cursor = deg + NNODES;
  int* bsums = cursor + NNODES;

  __hip_bfloat16* proj1 = proj0;  // aliases proj0 (dead after k_agg0w)
  float* es1 = esx0;              // layer-1 exp/att slots (esx0 dead after k_agg0w)

  // ---- fused weight prep ----
  k_prep<<<212, 256, 0, stream>>>(W0, a10, a20, a30, W1, Wskip1, a11, a21, a31,
                                  B0swz, B1swz);

  // ---- Layer-0 projection + scores via MFMA ----
  k_mm0<<<(NNODES + 63) / 64, 256, 0, stream>>>(x, (const short*)B0swz, proj0,
                                                s1_0, s2_0, s3_0);

  // ---- CSR build ----
  hipMemsetAsync(deg, 0, NNODES * sizeof(int), stream);
  k_deg<<<(2 * NEDGES + 255) / 256, 256, 0, stream>>>(ei, deg);
  k_scan1<<<NB_SCAN, 256, 0, stream>>>(deg, offs, bsums);
  k_scan2<<<1, 512, 0, stream>>>(bsums);
  k_scan3<<<NB_SCAN, 256, 0, stream>>>(offs, bsums, cursor);
  k_fill3<<<(2 * NEDGES + 255) / 256, 256, 0, stream>>>(ei, cursor, recA, rcvA);

  // ---- Layer 0: slot-parallel exp -> node sums -> slot-parallel att -> agg ---
  const int NBS = (2 * NEDGES + 255) / 256;
  k_esx0<<<NBS, 256, 0, stream>>>(recA, rcvA, s1_0, s2_0, s3_0, esx0);
  k_sums0n<<<NB_SCAN, 256, 0, stream>>>(offs, esx0, sums0);
  k_att0s<<<NBS, 256, 0, stream>>>(recA, rcvA, sums0, esx0);
  k_agg0w<<<(NNODES + 3) / 4, 256, 0, stream>>>(offs, recA, esx0, proj0, x, b0,
                                                out0b);

  // ---- Layer 1: MFMA GEMM -> slot exp -> sums -> att -> aggregate ----
  k_mm1<<<(NNODES + 63) / 64, 256, 0, stream>>>(out0b, (const short*)B1swz, b1,
                                                proj1, out, s1_1, s2_1, s3_1);
  k_esx1<<<NBS, 256, 0, stream>>>(recA, rcvA, s1_1, s2_1, s3_1, es1);
  k_sums1n<<<NB_SCAN, 256, 0, stream>>>(offs, es1, sums1);
  k_att1s<<<NBS, 256, 0, stream>>>(recA, rcvA, sums1, es1);
  k_agg1<<<(NNODES + 3) / 4, 256, 0, stream>>>(offs, recA, es1, proj1, out);
}